// Round 3
// baseline (1198.391 us; speedup 1.0000x reference)
//
#include <hip/hip_runtime.h>
#include <hip/hip_bf16.h>
#include <math.h>

// HelicalGNNFrontend: 2-layer GATv2 (heads=1, self-loops, mean loop edge_attr)
// N=50000 nodes, E=800000 edges, NODE_DIM=HID=128, EDGE_DIM=32.
//
// Round 3: 4-edge ILP batch in fused kernel (4 concurrent gathers + 4
// pipelined shfl-reduce chains + defer-max rescale), hierarchical scan.

#define HIP_N 50000
#define HIP_E 800000
#define HIP_H 128
#define HIP_ED 32
#define NEG_SLOPE 0.2f
#define RESCALE_THR 8.0f

// ---------------- edge-index dtype detection ----------------
__global__ void k_detect(const int* __restrict__ ei, int* __restrict__ is32) {
    int j = blockIdx.x * blockDim.x + threadIdx.x;   // j in [0, 4096)
    if (j < 4096) {
        if (ei[2 * j + 1] != 0) atomicOr(is32, 1);
    }
}

__device__ __forceinline__ int fetch_idx(const int* __restrict__ ei, int is32, long long pos) {
    return is32 ? ei[pos] : ei[2 * pos];  // little-endian low word for int64
}

// ---------------- CSR build ----------------
__global__ void k_hist(const int* __restrict__ ei, const int* __restrict__ flag,
                       int* __restrict__ deg) {
    int is32 = *flag;
    int e = blockIdx.x * blockDim.x + threadIdx.x;
    if (e < HIP_E) {
        int d = fetch_idx(ei, is32, (long long)HIP_E + e);
        atomicAdd(&deg[d], 1);
    }
}

// hierarchical scan: (1) per-1024-tile sums, (2) 1-wave scan of tile sums,
// (3) per-tile scan + base add
#define SCAN_TILE 1024
#define SCAN_NB ((HIP_N + SCAN_TILE - 1) / SCAN_TILE)   // 49

__global__ __launch_bounds__(256) void k_scan1(const int* __restrict__ deg,
                                               int* __restrict__ bsums) {
    __shared__ int ws[4];
    int b = blockIdx.x, t = threadIdx.x;
    int base = b * SCAN_TILE;
    int v = 0;
#pragma unroll
    for (int j = 0; j < 4; ++j) {
        int i = base + t + 256 * j;
        if (i < HIP_N) v += deg[i];
    }
#pragma unroll
    for (int off = 32; off > 0; off >>= 1) v += __shfl_xor(v, off);
    int lane = t & 63, wid = t >> 6;
    if (lane == 0) ws[wid] = v;
    __syncthreads();
    if (t == 0) bsums[b] = ws[0] + ws[1] + ws[2] + ws[3];
}

__global__ __launch_bounds__(64) void k_scan2(const int* __restrict__ bsums,
                                              int* __restrict__ bscan) {
    int t = threadIdx.x;
    int v = (t < SCAN_NB) ? bsums[t] : 0;
    int incl = v;
#pragma unroll
    for (int off = 1; off < 64; off <<= 1) {
        int u = __shfl_up(incl, off);
        if (t >= off) incl += u;
    }
    if (t < SCAN_NB) bscan[t] = incl - v;   // exclusive
}

__global__ __launch_bounds__(1024) void k_scan3(const int* __restrict__ deg,
                                                const int* __restrict__ bscan,
                                                int* __restrict__ offs,
                                                int* __restrict__ cursor) {
    __shared__ int wsum[16];
    int b = blockIdx.x, t = threadIdx.x;
    int i = b * SCAN_TILE + t;
    int lane = t & 63, wid = t >> 6;
    int v = (i < HIP_N) ? deg[i] : 0;
    int incl = v;
#pragma unroll
    for (int off = 1; off < 64; off <<= 1) {
        int u = __shfl_up(incl, off);
        if (lane >= off) incl += u;
    }
    if (lane == 63) wsum[wid] = incl;
    __syncthreads();
    if (wid == 0 && lane < 16) {
        int w = wsum[lane];
#pragma unroll
        for (int off = 1; off < 16; off <<= 1) {
            int u = __shfl_up(w, off);
            if (lane >= off) w += u;
        }
        wsum[lane] = w;   // inclusive over waves
    }
    __syncthreads();
    int baseadd = bscan[b] + (wid > 0 ? wsum[wid - 1] : 0);
    int excl = baseadd + incl - v;
    if (i < HIP_N) {
        offs[i] = excl;
        cursor[i] = excl;
        if (i == HIP_N - 1) offs[HIP_N] = excl + v;
    }
}

__global__ void k_scatter(const int* __restrict__ ei, const int* __restrict__ flag,
                          int* __restrict__ cursor, int* __restrict__ e_src,
                          int* __restrict__ e_id) {
    int is32 = *flag;
    int e = blockIdx.x * blockDim.x + threadIdx.x;
    if (e < HIP_E) {
        int s = fetch_idx(ei, is32, e);
        int d = fetch_idx(ei, is32, (long long)HIP_E + e);
        int pos = atomicAdd(&cursor[d], 1);
        e_src[pos] = s;
        e_id[pos] = e;
    }
}

// ea_sorted[pos] = ea[e_id[pos]]  (rows of 32 floats = 8 float4)
__global__ void k_permute_ea(const int* __restrict__ e_id, const float* __restrict__ ea,
                             float* __restrict__ ea_s) {
    long long idx = (long long)blockIdx.x * 256 + threadIdx.x;  // over E*8 float4s
    if (idx < (long long)HIP_E * 8) {
        int pos = (int)(idx >> 3), q = (int)(idx & 7);
        ((float4*)ea_s)[(size_t)pos * 8 + q] =
            ((const float4*)ea)[(size_t)e_id[pos] * 8 + q];
    }
}

// loop_attr[i][d] = (sum of incoming edge_attr) / max(deg,1)  (streams ea_sorted)
__global__ void k_loopattr(const int* __restrict__ offs, const float* __restrict__ ea_s,
                           float* __restrict__ loop_attr) {
    int node = blockIdx.x * 4 + (threadIdx.x >> 5);
    int d = threadIdx.x & 31;
    if (node < HIP_N) {
        int o0 = offs[node], o1 = offs[node + 1];
        float acc = 0.f;
        for (int e = o0; e < o1; ++e)
            acc += ea_s[(size_t)e * HIP_ED + d];
        float dg = (float)(o1 - o0);
        loop_attr[(size_t)node * HIP_ED + d] = acc / fmaxf(dg, 1.f);
    }
}

// ---------------- GEMMs (fp32, LDS-tiled, 32 rows/block) ----------------
__global__ __launch_bounds__(256) void k_emb(const float* __restrict__ x,
                                             const float* __restrict__ W,
                                             const float* __restrict__ b,
                                             float* __restrict__ h, int n) {
    __shared__ float tile[32][128];
    int rb = blockIdx.x * 32;
    int tid = threadIdx.x;
    for (int j = 0; j < 16; ++j) {
        int idx = j * 256 + tid;
        int r = idx >> 7, c = idx & 127;
        int row = rb + r;
        tile[r][c] = (row < n) ? x[(size_t)row * 128 + c] : 0.f;
    }
    __syncthreads();
    int c = tid & 127, g = tid >> 7;
    float acc[16];
#pragma unroll
    for (int r = 0; r < 16; ++r) acc[r] = 0.f;
    for (int d4 = 0; d4 < 32; ++d4) {
        int d = d4 * 4;
        float w0 = W[(d + 0) * 128 + c];
        float w1 = W[(d + 1) * 128 + c];
        float w2 = W[(d + 2) * 128 + c];
        float w3 = W[(d + 3) * 128 + c];
#pragma unroll
        for (int r = 0; r < 16; ++r) {
            const float4 hv = *(const float4*)&tile[g * 16 + r][d];
            acc[r] += hv.x * w0 + hv.y * w1 + hv.z * w2 + hv.w * w3;
        }
    }
    float bb = b[c];
    for (int r = 0; r < 16; ++r) {
        int row = rb + g * 16 + r;
        if (row < n) h[(size_t)row * 128 + c] = acc[r] + bb;
    }
}

__global__ __launch_bounds__(256) void k_lin(const float* __restrict__ h,
                                             const float* __restrict__ Wl,
                                             const float* __restrict__ bl,
                                             const float* __restrict__ Wr,
                                             float* __restrict__ xl,
                                             float* __restrict__ xr, int n) {
    __shared__ float tile[32][128];
    int rb = blockIdx.x * 32;
    int tid = threadIdx.x;
    for (int j = 0; j < 16; ++j) {
        int idx = j * 256 + tid;
        int r = idx >> 7, c = idx & 127;
        int row = rb + r;
        tile[r][c] = (row < n) ? h[(size_t)row * 128 + c] : 0.f;
    }
    __syncthreads();
    int c = tid & 127, g = tid >> 7;
    float accl[16], accr[16];
#pragma unroll
    for (int r = 0; r < 16; ++r) { accl[r] = 0.f; accr[r] = 0.f; }
    for (int d4 = 0; d4 < 32; ++d4) {
        int d = d4 * 4;
        float wl0 = Wl[(d + 0) * 128 + c];
        float wl1 = Wl[(d + 1) * 128 + c];
        float wl2 = Wl[(d + 2) * 128 + c];
        float wl3 = Wl[(d + 3) * 128 + c];
        float wr0 = Wr[(d + 0) * 128 + c];
        float wr1 = Wr[(d + 1) * 128 + c];
        float wr2 = Wr[(d + 2) * 128 + c];
        float wr3 = Wr[(d + 3) * 128 + c];
#pragma unroll
        for (int r = 0; r < 16; ++r) {
            const float4 hv = *(const float4*)&tile[g * 16 + r][d];
            accl[r] += hv.x * wl0 + hv.y * wl1 + hv.z * wl2 + hv.w * wl3;
            accr[r] += hv.x * wr0 + hv.y * wr1 + hv.z * wr2 + hv.w * wr3;
        }
    }
    float bb = bl[c];
    for (int r = 0; r < 16; ++r) {
        int row = rb + g * 16 + r;
        if (row < n) {
            xl[(size_t)row * 128 + c] = accl[r] + bb;
            xr[(size_t)row * 128 + c] = accr[r];
        }
    }
}

// ---------------- fused per-node online softmax + aggregation ----------------
// One WAVE per node; thread t owns feature dims (2t, 2t+1) as float2.
// 4 edges per iteration: 4 concurrent gathers + 4 pipelined shfl chains.
__global__ __launch_bounds__(256) void k_node_fused(
    const int* __restrict__ offs, const int* __restrict__ e_src,
    const float* __restrict__ ea_s, const float* __restrict__ loopat,
    const float* __restrict__ We, const float* __restrict__ att,
    const float* __restrict__ xl, const float* __restrict__ xr,
    const float* __restrict__ bo, float* __restrict__ hout) {
    int i = blockIdx.x * 4 + (threadIdx.x >> 6);
    int t = threadIdx.x & 63;
    if (i >= HIP_N) return;

    const float2* We2 = (const float2*)We;
    float2 Wreg[HIP_ED];
#pragma unroll
    for (int d = 0; d < HIP_ED; ++d) Wreg[d] = We2[d * 64 + t];

    float2 attv = ((const float2*)att)[t];
    float2 bov  = ((const float2*)bo)[t];
    float2 xri  = ((const float2*)(xr + (size_t)i * HIP_H))[t];
    float2 xli  = ((const float2*)(xl + (size_t)i * HIP_H))[t];

    // ---- self-loop logit ----
    const float4* la4 = (const float4*)(loopat + (size_t)i * HIP_ED);
    float epx = 0.f, epy = 0.f;
#pragma unroll
    for (int q = 0; q < 8; ++q) {
        float4 la = la4[q];
        epx += la.x * Wreg[q*4+0].x + la.y * Wreg[q*4+1].x
             + la.z * Wreg[q*4+2].x + la.w * Wreg[q*4+3].x;
        epy += la.x * Wreg[q*4+0].y + la.y * Wreg[q*4+1].y
             + la.z * Wreg[q*4+2].y + la.w * Wreg[q*4+3].y;
    }
    float mx = xli.x + xri.x + epx;
    float my = xli.y + xri.y + epy;
    mx = mx > 0.f ? mx : NEG_SLOPE * mx;
    my = my > 0.f ? my : NEG_SLOPE * my;
    float part = mx * attv.x + my * attv.y;
#pragma unroll
    for (int off = 32; off > 0; off >>= 1) part += __shfl_xor(part, off);

    float m = part;        // running max reference
    float denom = 1.f;     // exp(self - self) = 1
    float accx = xli.x, accy = xli.y;

    int o0 = offs[i], o1 = offs[i + 1];
    int e = o0;
    const float2* xl2 = (const float2*)xl;

    // ---- 4-wide main loop ----
    for (; e + 4 <= o1; e += 4) {
        int s0 = e_src[e], s1 = e_src[e+1], s2 = e_src[e+2], s3 = e_src[e+3];
        float2 x0 = xl2[(size_t)s0 * 64 + t];
        float2 x1 = xl2[(size_t)s1 * 64 + t];
        float2 x2 = xl2[(size_t)s2 * 64 + t];
        float2 x3 = xl2[(size_t)s3 * 64 + t];
        const float4* ea4 = (const float4*)(ea_s + (size_t)e * HIP_ED);
        float ex0=0.f,ey0=0.f, ex1=0.f,ey1=0.f, ex2=0.f,ey2=0.f, ex3=0.f,ey3=0.f;
#pragma unroll
        for (int q = 0; q < 8; ++q) {
            float4 a0 = ea4[q], a1 = ea4[8+q], a2 = ea4[16+q], a3 = ea4[24+q];
            float2 w0 = Wreg[q*4+0], w1 = Wreg[q*4+1], w2 = Wreg[q*4+2], w3 = Wreg[q*4+3];
            ex0 += a0.x*w0.x + a0.y*w1.x + a0.z*w2.x + a0.w*w3.x;
            ey0 += a0.x*w0.y + a0.y*w1.y + a0.z*w2.y + a0.w*w3.y;
            ex1 += a1.x*w0.x + a1.y*w1.x + a1.z*w2.x + a1.w*w3.x;
            ey1 += a1.x*w0.y + a1.y*w1.y + a1.z*w2.y + a1.w*w3.y;
            ex2 += a2.x*w0.x + a2.y*w1.x + a2.z*w2.x + a2.w*w3.x;
            ey2 += a2.x*w0.y + a2.y*w1.y + a2.z*w2.y + a2.w*w3.y;
            ex3 += a3.x*w0.x + a3.y*w1.x + a3.z*w2.x + a3.w*w3.x;
            ey3 += a3.x*w0.y + a3.y*w1.y + a3.z*w2.y + a3.w*w3.y;
        }
        float vx, vy;
        vx = x0.x + xri.x + ex0; vy = x0.y + xri.y + ey0;
        vx = vx > 0.f ? vx : NEG_SLOPE * vx; vy = vy > 0.f ? vy : NEG_SLOPE * vy;
        float p0 = vx * attv.x + vy * attv.y;
        vx = x1.x + xri.x + ex1; vy = x1.y + xri.y + ey1;
        vx = vx > 0.f ? vx : NEG_SLOPE * vx; vy = vy > 0.f ? vy : NEG_SLOPE * vy;
        float p1 = vx * attv.x + vy * attv.y;
        vx = x2.x + xri.x + ex2; vy = x2.y + xri.y + ey2;
        vx = vx > 0.f ? vx : NEG_SLOPE * vx; vy = vy > 0.f ? vy : NEG_SLOPE * vy;
        float p2 = vx * attv.x + vy * attv.y;
        vx = x3.x + xri.x + ex3; vy = x3.y + xri.y + ey3;
        vx = vx > 0.f ? vx : NEG_SLOPE * vx; vy = vy > 0.f ? vy : NEG_SLOPE * vy;
        float p3 = vx * attv.x + vy * attv.y;
#pragma unroll
        for (int off = 32; off > 0; off >>= 1) {
            p0 += __shfl_xor(p0, off);
            p1 += __shfl_xor(p1, off);
            p2 += __shfl_xor(p2, off);
            p3 += __shfl_xor(p3, off);
        }
        float pm = fmaxf(fmaxf(p0, p1), fmaxf(p2, p3));
        if (pm > m + RESCALE_THR) {        // defer-max: rescale rarely
            float sc = __expf(m - pm);
            accx *= sc; accy *= sc; denom *= sc;
            m = pm;
        }
        float w0 = __expf(p0 - m);
        float w1 = __expf(p1 - m);
        float w2 = __expf(p2 - m);
        float w3 = __expf(p3 - m);
        accx += w0 * x0.x + w1 * x1.x + w2 * x2.x + w3 * x3.x;
        accy += w0 * x0.y + w1 * x1.y + w2 * x2.y + w3 * x3.y;
        denom += w0 + w1 + w2 + w3;
    }

    // ---- tail ----
    for (; e < o1; ++e) {
        int s = e_src[e];
        float2 xlj = xl2[(size_t)s * 64 + t];
        const float4* ea4 = (const float4*)(ea_s + (size_t)e * HIP_ED);
        float ex = 0.f, ey = 0.f;
#pragma unroll
        for (int q = 0; q < 8; ++q) {
            float4 a = ea4[q];
            ex += a.x * Wreg[q*4+0].x + a.y * Wreg[q*4+1].x
                + a.z * Wreg[q*4+2].x + a.w * Wreg[q*4+3].x;
            ey += a.x * Wreg[q*4+0].y + a.y * Wreg[q*4+1].y
                + a.z * Wreg[q*4+2].y + a.w * Wreg[q*4+3].y;
        }
        float vx = xlj.x + xri.x + ex;
        float vy = xlj.y + xri.y + ey;
        vx = vx > 0.f ? vx : NEG_SLOPE * vx;
        vy = vy > 0.f ? vy : NEG_SLOPE * vy;
        float p = vx * attv.x + vy * attv.y;
#pragma unroll
        for (int off = 32; off > 0; off >>= 1) p += __shfl_xor(p, off);
        if (p > m + RESCALE_THR) {
            float sc = __expf(m - p);
            accx *= sc; accy *= sc; denom *= sc;
            m = p;
        }
        float w = __expf(p - m);
        accx += w * xlj.x;
        accy += w * xlj.y;
        denom += w;
    }

    float ox = accx / denom + bov.x;
    float oy = accy / denom + bov.y;
    float2 o;
    o.x = ox / (1.f + __expf(-ox));
    o.y = oy / (1.f + __expf(-oy));
    ((float2*)(hout + (size_t)i * HIP_H))[t] = o;
}

// ---------------- host launch ----------------
extern "C" void kernel_launch(void* const* d_in, const int* in_sizes, int n_in,
                              void* d_out, int out_size, void* d_ws, size_t ws_size,
                              hipStream_t stream) {
    const float* x      = (const float*)d_in[0];
    const int*   ei     = (const int*)d_in[1];
    const float* ea     = (const float*)d_in[2];
    const float* W_emb  = (const float*)d_in[3];
    const float* b_emb  = (const float*)d_in[4];
    const float* Wl1    = (const float*)d_in[5];
    const float* bl1    = (const float*)d_in[6];
    const float* Wr1    = (const float*)d_in[7];
    const float* We1    = (const float*)d_in[8];
    const float* att1   = (const float*)d_in[9];
    const float* bo1    = (const float*)d_in[10];
    const float* Wl2    = (const float*)d_in[11];
    const float* bl2    = (const float*)d_in[12];
    const float* Wr2    = (const float*)d_in[13];
    const float* We2    = (const float*)d_in[14];
    const float* att2   = (const float*)d_in[15];
    const float* bo2    = (const float*)d_in[16];
    float* out = (float*)d_out;

    char* p = (char*)d_ws;
    auto carve = [&](size_t bytes) {
        void* q = (void*)p;
        p += (bytes + 255) / 256 * 256;
        return q;
    };
    float* h        = (float*)carve((size_t)HIP_N * 128 * 4);
    float* xl       = (float*)carve((size_t)HIP_N * 128 * 4);
    float* xr       = (float*)carve((size_t)HIP_N * 128 * 4);
    float* loopat   = (float*)carve((size_t)HIP_N * HIP_ED * 4);
    float* ea_s     = (float*)carve((size_t)HIP_E * HIP_ED * 4);
    int*   deg      = (int*)carve((size_t)HIP_N * 4);
    int*   offs     = (int*)carve((size_t)(HIP_N + 1) * 4);
    int*   cursor   = (int*)carve((size_t)HIP_N * 4);
    int*   e_src    = (int*)carve((size_t)HIP_E * 4);
    int*   e_id     = (int*)carve((size_t)HIP_E * 4);
    int*   flag     = (int*)carve(256);
    int*   bsums    = (int*)carve((size_t)SCAN_NB * 4);
    int*   bscan    = (int*)carve((size_t)SCAN_NB * 4);

    hipMemsetAsync(deg, 0, (size_t)HIP_N * 4, stream);
    hipMemsetAsync(flag, 0, 4, stream);

    k_detect<<<16, 256, 0, stream>>>(ei, flag);
    k_hist<<<(HIP_E + 255) / 256, 256, 0, stream>>>(ei, flag, deg);
    k_scan1<<<SCAN_NB, 256, 0, stream>>>(deg, bsums);
    k_scan2<<<1, 64, 0, stream>>>(bsums, bscan);
    k_scan3<<<SCAN_NB, 1024, 0, stream>>>(deg, bscan, offs, cursor);
    k_scatter<<<(HIP_E + 255) / 256, 256, 0, stream>>>(ei, flag, cursor, e_src, e_id);
    k_permute_ea<<<(HIP_E * 8 + 255) / 256, 256, 0, stream>>>(e_id, ea, ea_s);
    k_loopattr<<<(HIP_N + 3) / 4, 128, 0, stream>>>(offs, ea_s, loopat);

    int gemm_grid = (HIP_N + 31) / 32;
    k_emb<<<gemm_grid, 256, 0, stream>>>(x, W_emb, b_emb, h, HIP_N);

    int fuse_grid = (HIP_N + 3) / 4;
    // ----- layer 1 -----
    k_lin<<<gemm_grid, 256, 0, stream>>>(h, Wl1, bl1, Wr1, xl, xr, HIP_N);
    k_node_fused<<<fuse_grid, 256, 0, stream>>>(offs, e_src, ea_s, loopat, We1, att1,
                                                xl, xr, bo1, h);
    // ----- layer 2 -----
    k_lin<<<gemm_grid, 256, 0, stream>>>(h, Wl2, bl2, Wr2, xl, xr, HIP_N);
    k_node_fused<<<fuse_grid, 256, 0, stream>>>(offs, e_src, ea_s, loopat, We2, att2,
                                                xl, xr, bo2, out);
}